// Round 2
// baseline (178.930 us; speedup 1.0000x reference)
//
#include <hip/hip_runtime.h>

#define TT 1024
#define SS 128
#define FF 8
#define CC 256
#define BH 8

// Inclusive prefix sum of each batch row of d (int32 on device) -> cum.
__global__ void scan_kernel(const int* __restrict__ d, int* __restrict__ cum) {
    __shared__ int buf[SS];
    int b = blockIdx.x;
    int s = threadIdx.x;
    buf[s] = d[b * SS + s];
    __syncthreads();
    for (int off = 1; off < SS; off <<= 1) {
        int v = (s >= off) ? buf[s - off] : 0;
        __syncthreads();
        buf[s] += v;
        __syncthreads();
    }
    cum[b * SS + s] = buf[s];
}

// One block per (s, b): stream the contiguous segment [start,end) x F x C,
// accumulate per-channel, divide by d*F.
__global__ __launch_bounds__(256) void agg_kernel(const float* __restrict__ e,
                                                  const int* __restrict__ dsrc,
                                                  const int* __restrict__ cum,
                                                  float* __restrict__ out) {
    int s = blockIdx.x;
    int b = blockIdx.y;
    int tid = threadIdx.x;
    int c4 = tid & 63;   // which group of 4 channels (256/4 = 64)
    int q  = tid >> 6;   // 4 sub-groups splitting the k loop

    int end   = cum[b * SS + s];
    int start = (s == 0) ? 0 : cum[b * SS + s - 1];
    int dc    = dsrc[b * SS + s];
    if (start > TT) start = TT;
    if (end   > TT) end   = TT;
    int K = (end - start) * FF;   // number of 256-float rows (each = 64 float4)

    const float4* e4 = (const float4*)(e + (size_t)(b * TT + start) * (FF * CC));

    float ax = 0.f, ay = 0.f, az = 0.f, aw = 0.f;
    for (int k = q; k < K; k += 4) {
        float4 v = e4[(size_t)k * 64 + c4];
        ax += v.x; ay += v.y; az += v.z; aw += v.w;
    }

    __shared__ float4 red[256];
    red[tid] = make_float4(ax, ay, az, aw);
    __syncthreads();

    if (q == 0) {
        float4 r0 = red[tid];
        float4 r1 = red[tid + 64];
        float4 r2 = red[tid + 128];
        float4 r3 = red[tid + 192];
        float inv = (dc > 0) ? (1.0f / (float)(dc * FF)) : 0.0f;
        float4 r;
        r.x = (r0.x + r1.x + r2.x + r3.x) * inv;
        r.y = (r0.y + r1.y + r2.y + r3.y) * inv;
        r.z = (r0.z + r1.z + r2.z + r3.z) * inv;
        r.w = (r0.w + r1.w + r2.w + r3.w) * inv;
        ((float4*)out)[(size_t)(b * SS + s) * 64 + c4] = r;
    }
}

extern "C" void kernel_launch(void* const* d_in, const int* in_sizes, int n_in,
                              void* d_out, int out_size, void* d_ws, size_t ws_size,
                              hipStream_t stream) {
    const float* e   = (const float*)d_in[0];
    const int*   d   = (const int*)d_in[1];
    float*       out = (float*)d_out;
    int*         cum = (int*)d_ws;   // BH*SS ints = 4 KB

    scan_kernel<<<BH, SS, 0, stream>>>(d, cum);
    agg_kernel<<<dim3(SS, BH), 256, 0, stream>>>(e, d, cum, out);
}

// Round 3
// 174.837 us; speedup vs baseline: 1.0234x; 1.0234x over previous
//
#include <hip/hip_runtime.h>

#define TT 1024
#define SS 128
#define FF 8
#define CC 256
#define BH 8

// Fused: per-block LDS scan of the d row (cheap, redundant across blocks),
// then stream the contiguous segment [start,end) x F x C and reduce.
__global__ __launch_bounds__(256) void fused_kernel(const float* __restrict__ e,
                                                    const int* __restrict__ dsrc,
                                                    float* __restrict__ out) {
    int s = blockIdx.x;
    int b = blockIdx.y;
    int tid = threadIdx.x;
    int c4 = tid & 63;   // group of 4 channels (256/4 = 64)
    int q  = tid >> 6;   // 4 sub-groups splitting the k loop

    // --- inclusive scan of d[b, :] in LDS (threads 0..127 participate) ---
    __shared__ int cumbuf[SS];
    if (tid < SS) cumbuf[tid] = dsrc[b * SS + tid];
    __syncthreads();
    #pragma unroll
    for (int off = 1; off < SS; off <<= 1) {
        int v = 0;
        if (tid < SS && tid >= off) v = cumbuf[tid - off];
        __syncthreads();
        if (tid < SS) cumbuf[tid] += v;
        __syncthreads();
    }

    int end   = cumbuf[s];
    int start = (s == 0) ? 0 : cumbuf[s - 1];
    int dc    = dsrc[b * SS + s];
    if (start > TT) start = TT;
    if (end   > TT) end   = TT;
    int K = (end - start) * FF;   // number of 256-float rows (each = 64 float4)

    const float4* e4 = (const float4*)(e + (size_t)(b * TT + start) * (FF * CC));

    float ax = 0.f, ay = 0.f, az = 0.f, aw = 0.f;
    int k = q;
    // 4 independent loads in flight per thread for memory-level parallelism
    for (; k + 12 < K; k += 16) {
        float4 v0 = e4[(size_t)(k     ) * 64 + c4];
        float4 v1 = e4[(size_t)(k +  4) * 64 + c4];
        float4 v2 = e4[(size_t)(k +  8) * 64 + c4];
        float4 v3 = e4[(size_t)(k + 12) * 64 + c4];
        ax += v0.x + v1.x + v2.x + v3.x;
        ay += v0.y + v1.y + v2.y + v3.y;
        az += v0.z + v1.z + v2.z + v3.z;
        aw += v0.w + v1.w + v2.w + v3.w;
    }
    for (; k < K; k += 4) {
        float4 v = e4[(size_t)k * 64 + c4];
        ax += v.x; ay += v.y; az += v.z; aw += v.w;
    }

    __shared__ float4 red[256];
    red[tid] = make_float4(ax, ay, az, aw);
    __syncthreads();

    if (q == 0) {
        float4 r0 = red[tid];
        float4 r1 = red[tid + 64];
        float4 r2 = red[tid + 128];
        float4 r3 = red[tid + 192];
        float inv = (dc > 0) ? (1.0f / (float)(dc * FF)) : 0.0f;
        float4 r;
        r.x = (r0.x + r1.x + r2.x + r3.x) * inv;
        r.y = (r0.y + r1.y + r2.y + r3.y) * inv;
        r.z = (r0.z + r1.z + r2.z + r3.z) * inv;
        r.w = (r0.w + r1.w + r2.w + r3.w) * inv;
        ((float4*)out)[(size_t)(b * SS + s) * 64 + c4] = r;
    }
}

extern "C" void kernel_launch(void* const* d_in, const int* in_sizes, int n_in,
                              void* d_out, int out_size, void* d_ws, size_t ws_size,
                              hipStream_t stream) {
    const float* e   = (const float*)d_in[0];
    const int*   d   = (const int*)d_in[1];
    float*       out = (float*)d_out;

    fused_kernel<<<dim3(SS, BH), 256, 0, stream>>>(e, d, out);
}